// Round 7
// baseline (468.708 us; speedup 1.0000x reference)
//
#include <hip/hip_runtime.h>
#include <hip/hip_bf16.h>

// SelfAttention non-local block: B=8, C=512, N=4096, CQK=32.  All-MFMA bf16 path.
// v9 (resubmission — round-6 bench failed on container acquisition):
//  - k_pass2 re-tiled for cross-block phase skew: grid 512 = 8b x 64 ntb, blocks
//    of 256 thr (4 waves), each block 512c x 64n. v8 had 1 block/CU whose 8 waves
//    (2/SIMD, same barrier cohort) marched in lockstep -> per-chunk time ~= SUM of
//    pipe times (6130 cyc vs MFMA 2640). Now 2 independent blocks/CU: the two
//    SIMD-resident waves have independent barriers -> phases skew -> pipes overlap.
//    n is partitioned (not duplicated): P work chip-wide unchanged. Per-CU P
//    ds_read traffic halves (128c-wide waves re-read P less). Per-wave cost
//    identical to v8 (68 MFMA, 8 b128 P-reads, 4 produce tiles, ~same VGPR).
//  - keeps v8 raw chunk_barrier (lgkm-only drain; global prefetches in flight).
// ws: vb 33.5MB | xT 33.5MB | qb 2MB | kb 2MB | Wvb 512KB | Wqb 32KB | Wkb 32KB | Lneg 128KB

typedef __attribute__((ext_vector_type(8))) short s16x8;
typedef __attribute__((ext_vector_type(4))) float f32x4;

#define MFMA16(a, b, c) __builtin_amdgcn_mfma_f32_16x16x32_bf16((a), (b), (c), 0, 0, 0)

__device__ __forceinline__ ushort f2bf(float f) {
  union { float f; unsigned u; } v; v.f = f;
  return (ushort)((v.u + 0x8000u) >> 16);
}
__device__ __forceinline__ unsigned pack_bf16(float lo, float hi) {  // (hi<<16)|lo
  union { float f; unsigned u; } a, b; a.f = lo; b.f = hi;
  return __builtin_amdgcn_perm(b.u + 0x8000u, a.u + 0x8000u, 0x07060302u);
}
__device__ __forceinline__ float fexp2(float x) { return __builtin_amdgcn_exp2f(x); }

// Raw chunk barrier: publish DS writes, sync, but leave global loads in flight.
__device__ __forceinline__ void chunk_barrier() {
  asm volatile("s_waitcnt lgkmcnt(0)" ::: "memory");
  __builtin_amdgcn_s_barrier();
  __builtin_amdgcn_sched_barrier(0);
}

// ---------------- kernel 1: weights -> bf16 (Wq pre-scaled by log2e) ----------------
__global__ void k_cvt_w(const float* __restrict__ Wq, const float* __restrict__ Wk,
                        const float* __restrict__ Wv, ushort* __restrict__ Wqb,
                        ushort* __restrict__ Wkb, ushort* __restrict__ Wvb) {
  int i = blockIdx.x * 256 + threadIdx.x;
  if (i < 262144) Wvb[i] = f2bf(Wv[i]);
  else if (i < 278528) Wqb[i - 262144] = f2bf(Wq[i - 262144] * 1.4426950408889634f);
  else if (i < 294912) Wkb[i - 278528] = f2bf(Wk[i - 278528]);
}

// ---------------- kernel 2: transpose x -> xT bf16 ----------------
// Tile 64c x 256n. Phase1: float4 row loads (1KB contiguous per row), pack n-pairs,
// SoA LDS U[2][64][65] (even/odd pair split => <=2-way banks). Phase2: 8-lane groups
// build 128B-contiguous xT rows via v_perm extraction.
__global__ __launch_bounds__(256) void k_xpose(const float* __restrict__ x,
                                               ushort* __restrict__ xT) {
  const int b = blockIdx.z, c0 = blockIdx.y * 64, n0 = blockIdx.x * 256;
  __shared__ uint U[2][64][65];
  const int t = threadIdx.x;
  const int wv = t >> 6, ln = t & 63;
  const float* xp = x + ((size_t)b * 512 + c0 + wv * 16) * 4096 + n0 + ln * 4;
#pragma unroll
  for (int i = 0; i < 16; ++i) {
    float4 f = *(const float4*)(xp + (size_t)i * 4096);
    U[0][wv * 16 + i][ln] = pack_bf16(f.x, f.y);   // pairs (4ln,4ln+1)   -> pair idx 2ln
    U[1][wv * 16 + i][ln] = pack_bf16(f.z, f.w);   // pairs (4ln+2,4ln+3) -> pair idx 2ln+1
  }
  __syncthreads();
  const int c_seg = (t & 7) * 8;
#pragma unroll
  for (int pass = 0; pass < 8; ++pass) {
    const int nl = pass * 32 + (t >> 3);
    const int p = nl >> 1;              // pair index
    const int h = p & 1, idx = p >> 1;  // SoA half, slot
    const uint sel = (nl & 1) ? 0x07060302u : 0x05040100u;
    uint o[4];
#pragma unroll
    for (int j = 0; j < 4; ++j) {
      uint ua = U[h][c_seg + 2 * j][idx];
      uint ub = U[h][c_seg + 2 * j + 1][idx];
      o[j] = __builtin_amdgcn_perm(ub, ua, sel);   // (bf(c_odd)<<16)|bf(c_even)
    }
    *(uint4*)(xT + ((size_t)b * 4096 + n0 + nl) * 512 + c0 + c_seg) = *(uint4*)o;
  }
}

// ---------------- kernel 3: fused q/k/v projection from xT ----------------
__global__ __launch_bounds__(256, 2) void k_proj(const ushort* __restrict__ xT,
                                                 const ushort* __restrict__ Wqb,
                                                 const ushort* __restrict__ Wkb,
                                                 const ushort* __restrict__ Wvb,
                                                 ushort* __restrict__ qb,
                                                 ushort* __restrict__ kb,
                                                 ushort* __restrict__ vb) {
  const int b = blockIdx.y, n0 = blockIdx.x * 64;
  const int lane = threadIdx.x & 63, w = threadIdx.x >> 6;
  const int quad = lane >> 4, l15 = lane & 15;
  const ushort* xT_b = xT + (size_t)b * 4096 * 512;

  const ushort* Wqk = (w < 2) ? (Wqb + (size_t)(w * 16 + l15) * 512)
                              : (Wkb + (size_t)((w - 2) * 16 + l15) * 512);

  f32x4 accv[8][4], accqk[4];
#pragma unroll
  for (int i = 0; i < 8; ++i)
#pragma unroll
    for (int nt = 0; nt < 4; ++nt) accv[i][nt] = {0.f, 0.f, 0.f, 0.f};
#pragma unroll
  for (int nt = 0; nt < 4; ++nt) accqk[nt] = {0.f, 0.f, 0.f, 0.f};

  for (int k0 = 0; k0 < 512; k0 += 32) {
    s16x8 bx[4];
#pragma unroll
    for (int nt = 0; nt < 4; ++nt)
      bx[nt] = *(const s16x8*)(xT_b + (size_t)(n0 + nt * 16 + l15) * 512 + k0 + quad * 8);
#pragma unroll
    for (int i = 0; i < 8; ++i) {
      s16x8 av = *(const s16x8*)(Wvb + (size_t)((8 * w + i) * 16 + l15) * 512 + k0 + quad * 8);
#pragma unroll
      for (int nt = 0; nt < 4; ++nt) accv[i][nt] = MFMA16(av, bx[nt], accv[i][nt]);
    }
    s16x8 aqk = *(const s16x8*)(Wqk + k0 + quad * 8);
#pragma unroll
    for (int nt = 0; nt < 4; ++nt) accqk[nt] = MFMA16(aqk, bx[nt], accqk[nt]);
  }

  ushort* vb_b = vb + (size_t)b * 512 * 4096;
#pragma unroll
  for (int i = 0; i < 8; ++i)
#pragma unroll
    for (int nt = 0; nt < 4; ++nt)
#pragma unroll
      for (int r = 0; r < 4; ++r)
        vb_b[(size_t)((8 * w + i) * 16 + quad * 4 + r) * 4096 + n0 + nt * 16 + l15] =
            f2bf(accv[i][nt][r]);

  ushort* qk_out = (w < 2) ? (qb + (size_t)b * 4096 * 32) : (kb + (size_t)b * 4096 * 32);
#pragma unroll
  for (int nt = 0; nt < 4; ++nt) {
    ushort4 u;
    u.x = f2bf(accqk[nt][0]); u.y = f2bf(accqk[nt][1]);
    u.z = f2bf(accqk[nt][2]); u.w = f2bf(accqk[nt][3]);
    *(ushort4*)(qk_out + (size_t)(n0 + nt * 16 + l15) * 32 + (w & 1) * 16 + quad * 4) = u;
  }
}

// ---------------- kernel 4: pass1 — Lneg[b][m] = -log2(sum_n 2^(S'[m,n])) ----------------
__global__ __launch_bounds__(256) void k_pass1(const ushort* __restrict__ qb,
                                               const ushort* __restrict__ kb,
                                               float* __restrict__ Lneg) {
  const int b = blockIdx.y, mt = blockIdx.x;
  const int lane = threadIdx.x & 63, w = threadIdx.x >> 6;
  const int quad = lane >> 4, l15 = lane & 15;
  const int m = mt * 64 + w * 16;
  const ushort* qb_b = qb + (size_t)b * 4096 * 32;
  const ushort* kb_b = kb + (size_t)b * 4096 * 32;
  const s16x8 aqf = *(const s16x8*)(qb_b + (size_t)(m + l15) * 32 + quad * 8);
  float ps[4] = {0.f, 0.f, 0.f, 0.f};
  const f32x4 zf = {0.f, 0.f, 0.f, 0.f};
  for (int n0 = 0; n0 < 4096; n0 += 64) {
#pragma unroll
    for (int nt = 0; nt < 4; ++nt) {
      s16x8 bk = *(const s16x8*)(kb_b + (size_t)(n0 + nt * 16 + l15) * 32 + quad * 8);
      f32x4 s = MFMA16(aqf, bk, zf);
#pragma unroll
      for (int r = 0; r < 4; ++r) ps[r] += fexp2(s[r]);
    }
  }
  for (int off = 1; off < 16; off <<= 1)
#pragma unroll
    for (int r = 0; r < 4; ++r) ps[r] += __shfl_xor(ps[r], off, 64);
  if (l15 == 0)
#pragma unroll
    for (int r = 0; r < 4; ++r)
      Lneg[(size_t)b * 4096 + m + quad * 4 + r] = -log2f(ps[r]);
}

// ---------------- kernel 5: pass2 — out = V @ 2^(S' + Lneg) ----------------
// Grid 512 = 8 b (XCD-aligned: blk&7) x 64 ntb. Block 4 waves (256 thr): tile
// 512c x 64n, chunk 64 m; 2 independent blocks/CU -> SIMD-resident waves come
// from different barrier cohorts and phase-skew naturally. Per chunk: raw
// barrier (lgkm only) -> 4 P-reads (m0..31) -> produce x4 (reg-only inputs) ->
// loadQ -> consume half1 (va0, rr issue per-nt) -> loadV0 -> consume half2
// (va1) -> loadV1.  Global prefetches stay in flight across the barrier.
__global__ __launch_bounds__(256, 2) void k_pass2(const ushort* __restrict__ qb,
                                                  const ushort* __restrict__ kb,
                                                  const ushort* __restrict__ vb,
                                                  const float* __restrict__ Lneg,
                                                  float* __restrict__ out) {
  const int blk = blockIdx.x;
  const int b = blk & 7, ntb = blk >> 3;      // 64 ntb
  const int nbase = ntb * 64;
  const int lane = threadIdx.x & 63, w = threadIdx.x >> 6;   // 4 waves
  const int quad = lane >> 4, l15 = lane & 15;
  const int cbase = w * 128;                  // wave covers 128 c
  const int swz = l15 & 7;
  const int Mw = w;                           // produce m-tile (0..3)

  __shared__ __align__(16) ushort PT[2][64 * 64];  // 8 KB each; 16B-granule XOR swizzle

  const ushort* qb_b = qb + (size_t)b * 4096 * 32;
  const ushort* kb_b = kb + (size_t)b * 4096 * 32;
  const ushort* vb_b = vb + (size_t)b * 512 * 4096;
  const float* L_b = Lneg + (size_t)b * 4096;

  s16x8 kf[4];  // K rows for the block's 4 produce n-tiles
#pragma unroll
  for (int i = 0; i < 4; ++i)
    kf[i] = *(const s16x8*)(kb_b + (size_t)(nbase + i * 16 + l15) * 32 + quad * 8);

  f32x4 acc[8][4];  // [ci][nt]: 128c x 64n
#pragma unroll
  for (int ci = 0; ci < 8; ++ci)
#pragma unroll
    for (int nt = 0; nt < 4; ++nt) acc[ci][nt] = {0.f, 0.f, 0.f, 0.f};

  s16x8 aqp;        // prefetched q A-frag for next produce (single m-tile)
  float4 l4p;       // prefetched Lneg
  s16x8 va0[8], va1[8];  // v A-frags: m0..31 / m32..63 of current chunk

  auto loadQ = [&](int chunk) {
    const int m0 = chunk * 64;
    aqp = *(const s16x8*)(qb_b + (size_t)(m0 + Mw * 16 + l15) * 32 + quad * 8);
    l4p = *(const float4*)(L_b + m0 + Mw * 16 + quad * 4);
  };
  auto loadV0 = [&](int chunk) {
    const int m0 = chunk * 64;
#pragma unroll
    for (int ci = 0; ci < 8; ++ci)
      va0[ci] = *(const s16x8*)(vb_b + (size_t)(cbase + ci * 16 + l15) * 4096 + m0 + quad * 8);
  };
  auto loadV1 = [&](int chunk) {
    const int m0 = chunk * 64;
#pragma unroll
    for (int ci = 0; ci < 8; ++ci)
      va1[ci] = *(const s16x8*)(vb_b + (size_t)(cbase + ci * 16 + l15) * 4096 + m0 + 32 + quad * 8);
  };
  // one produce tile: QK MFMA (Lneg as C-in) -> exp2 -> pack -> ds_write.
  // Wave w produces m-tile Mw=w for n-tile T=i (0..3).
  auto produce_tile = [&](int buf, int i) {
    char* Pw = (char*)&PT[buf][0];
    f32x4 cin; cin.x = l4p.x; cin.y = l4p.y; cin.z = l4p.z; cin.w = l4p.w;
    f32x4 s = MFMA16(aqp, kf[i], cin);               // S' + Lneg  (<= ~0)
    uint2 u;
    u.x = pack_bf16(fexp2(s.x), fexp2(s.y));
    u.y = pack_bf16(fexp2(s.z), fexp2(s.w));
    const int row = i * 16 + l15;
    const int gran = (2 * Mw + (quad >> 1)) ^ swz;
    *(uint2*)(Pw + row * 128 + gran * 16 + (quad & 1) * 8) = u;
  };

  loadQ(0);
#pragma unroll
  for (int i = 0; i < 4; ++i) produce_tile(0, i);    // prologue: produce chunk 0
  loadQ(1);
  loadV0(0);
  loadV1(0);

  for (int chunk = 0; chunk < 64; ++chunk) {
    const int buf = chunk & 1;
    chunk_barrier();   // lgkm drain + s_barrier; global prefetches stay in flight
    const char* P = (const char*)&PT[buf][0];
    // --- issue half1 P reads (m0..31, nt 0..3) ---
    s16x8 pg[4];
#pragma unroll
    for (int nt = 0; nt < 4; ++nt)
      pg[nt] = *(const s16x8*)(P + (nt * 16 + l15) * 128 + (quad ^ swz) * 16);
    // --- produce chunk+1 into buf^1: register-only inputs, no dep on pg ---
    // (chunk 63's produce reuses aqp(63) and writes a never-read buffer: safe.)
#pragma unroll
    for (int i = 0; i < 4; ++i) produce_tile(buf ^ 1, i);
    if (chunk < 62) loadQ(chunk + 2);   // after produce (produce consumed aqp)
    // --- consume half1 (va0, m0..31); interleave rr issue per nt ---
    s16x8 rr[4];
#pragma unroll
    for (int nt = 0; nt < 4; ++nt) {
#pragma unroll
      for (int ci = 0; ci < 8; ++ci) acc[ci][nt] = MFMA16(va0[ci], pg[nt], acc[ci][nt]);
      rr[nt] = *(const s16x8*)(P + (nt * 16 + l15) * 128 + ((4 + quad) ^ swz) * 16);
    }
    // --- va0 dead: prefetch next chunk's va0 (L2 latency hides under half2) ---
    if (chunk < 63) loadV0(chunk + 1);
    // --- consume half2 (va1, m32..63) ---
#pragma unroll
    for (int nt = 0; nt < 4; ++nt)
#pragma unroll
      for (int ci = 0; ci < 8; ++ci) acc[ci][nt] = MFMA16(va1[ci], rr[nt], acc[ci][nt]);
    // --- prefetch next chunk's va1 ---
    if (chunk < 63) loadV1(chunk + 1);
  }

  float* out_b = out + (size_t)b * 512 * 4096;
#pragma unroll
  for (int ci = 0; ci < 8; ++ci)
#pragma unroll
    for (int nt = 0; nt < 4; ++nt) {
      const int n = nbase + nt * 16 + l15;
      const int c0 = cbase + ci * 16 + quad * 4;
#pragma unroll
      for (int r = 0; r < 4; ++r) out_b[(size_t)(c0 + r) * 4096 + n] = acc[ci][nt][r];
    }
}

// ---------------- launch ----------------
extern "C" void kernel_launch(void* const* d_in, const int* in_sizes, int n_in,
                              void* d_out, int out_size, void* d_ws, size_t ws_size,
                              hipStream_t stream) {
  const float* x  = (const float*)d_in[0];   // [8,512,64,64]
  const float* Wq = (const float*)d_in[1];   // [32,512]
  const float* Wk = (const float*)d_in[2];   // [32,512]
  const float* Wv = (const float*)d_in[3];   // [512,512]
  float* out = (float*)d_out;                // [8,512,64,64]

  char* ws = (char*)d_ws;
  ushort* vb  = (ushort*)(ws + 0);           // 33,554,432 B
  ushort* xT  = (ushort*)(ws + 33554432);    // 33,554,432 B
  ushort* qb  = (ushort*)(ws + 67108864);    //  2,097,152 B
  ushort* kb  = (ushort*)(ws + 69206016);    //  2,097,152 B
  ushort* Wvb = (ushort*)(ws + 71303168);    //    524,288 B
  ushort* Wqb = (ushort*)(ws + 71827456);    //     32,768 B
  ushort* Wkb = (ushort*)(ws + 71860224);    //     32,768 B
  float*  Lrs = (float*)(ws + 71892992);     //    131,072 B  (total 72,024,064)

  hipLaunchKernelGGL(k_cvt_w, dim3(1152), dim3(256), 0, stream, Wq, Wk, Wv, Wqb, Wkb, Wvb);
  hipLaunchKernelGGL(k_xpose, dim3(16, 8, 8), dim3(256), 0, stream, x, xT);
  hipLaunchKernelGGL(k_proj, dim3(64, 8), dim3(256), 0, stream, xT, Wqb, Wkb, Wvb, qb, kb, vb);
  hipLaunchKernelGGL(k_pass1, dim3(64, 8), dim3(256), 0, stream, qb, kb, Lrs);
  hipLaunchKernelGGL(k_pass2, dim3(512), dim3(256), 0, stream, qb, kb, vb, Lrs, out);
}

// Round 8
// 357.775 us; speedup vs baseline: 1.3101x; 1.3101x over previous
//
#include <hip/hip_runtime.h>
#include <hip/hip_bf16.h>

// SelfAttention non-local block: B=8, C=512, N=4096, CQK=32.  All-MFMA bf16 path.
// v10 = v8 pipeline + v5 tiling (clean test of barrier-lockstep theory):
//  - v9 FAILED (280us, FETCH 2x): halving n-tile doubled V read traffic through
//    the per-XCD L2 (V[b] is L2-resident, 32x reuse at n_tile=128). V traffic
//    scales as (N/n_tile)*|V| -- n_tile must stay 128.
//  - v10 gets 2 independent blocks/CU by splitting C instead: 2 blocks of
//    256c x 128n (grid 512 = 8b x 32ntb x 2cb). V traffic per CU unchanged
//    (each block reads its own 256c half). Cost: P produce duplicated per block
//    (+4 MFMA/wave, +16 exp2/lane per chunk -- measured ~6us at v5->v6), now
//    with v8's cheap produce (raw v_exp, produce hoisted after P-read issue).
//    Gain if lockstep theory holds: SIMD-resident waves from different barrier
//    cohorts phase-skew -> LDS/VALU phases of one block fill the other's MFMA
//    gaps (v8 measured per-chunk ~= SUM of pipes, 6130 cyc vs MFMA 2640).
//  - keeps v8 raw chunk_barrier (lgkm-only drain; global prefetches in flight).
// ws: vb 33.5MB | xT 33.5MB | qb 2MB | kb 2MB | Wvb 512KB | Wqb 32KB | Wkb 32KB | Lneg 128KB

typedef __attribute__((ext_vector_type(8))) short s16x8;
typedef __attribute__((ext_vector_type(4))) float f32x4;

#define MFMA16(a, b, c) __builtin_amdgcn_mfma_f32_16x16x32_bf16((a), (b), (c), 0, 0, 0)

__device__ __forceinline__ ushort f2bf(float f) {
  union { float f; unsigned u; } v; v.f = f;
  return (ushort)((v.u + 0x8000u) >> 16);
}
__device__ __forceinline__ unsigned pack_bf16(float lo, float hi) {  // (hi<<16)|lo
  union { float f; unsigned u; } a, b; a.f = lo; b.f = hi;
  return __builtin_amdgcn_perm(b.u + 0x8000u, a.u + 0x8000u, 0x07060302u);
}
__device__ __forceinline__ float fexp2(float x) { return __builtin_amdgcn_exp2f(x); }

// Raw chunk barrier: publish DS writes, sync, but leave global loads in flight.
__device__ __forceinline__ void chunk_barrier() {
  asm volatile("s_waitcnt lgkmcnt(0)" ::: "memory");
  __builtin_amdgcn_s_barrier();
  __builtin_amdgcn_sched_barrier(0);
}

// ---------------- kernel 1: weights -> bf16 (Wq pre-scaled by log2e) ----------------
__global__ void k_cvt_w(const float* __restrict__ Wq, const float* __restrict__ Wk,
                        const float* __restrict__ Wv, ushort* __restrict__ Wqb,
                        ushort* __restrict__ Wkb, ushort* __restrict__ Wvb) {
  int i = blockIdx.x * 256 + threadIdx.x;
  if (i < 262144) Wvb[i] = f2bf(Wv[i]);
  else if (i < 278528) Wqb[i - 262144] = f2bf(Wq[i - 262144] * 1.4426950408889634f);
  else if (i < 294912) Wkb[i - 278528] = f2bf(Wk[i - 278528]);
}

// ---------------- kernel 2: transpose x -> xT bf16 ----------------
// Tile 64c x 256n. Phase1: float4 row loads (1KB contiguous per row), pack n-pairs,
// SoA LDS U[2][64][65] (even/odd pair split => <=2-way banks). Phase2: 8-lane groups
// build 128B-contiguous xT rows via v_perm extraction.
__global__ __launch_bounds__(256) void k_xpose(const float* __restrict__ x,
                                               ushort* __restrict__ xT) {
  const int b = blockIdx.z, c0 = blockIdx.y * 64, n0 = blockIdx.x * 256;
  __shared__ uint U[2][64][65];
  const int t = threadIdx.x;
  const int wv = t >> 6, ln = t & 63;
  const float* xp = x + ((size_t)b * 512 + c0 + wv * 16) * 4096 + n0 + ln * 4;
#pragma unroll
  for (int i = 0; i < 16; ++i) {
    float4 f = *(const float4*)(xp + (size_t)i * 4096);
    U[0][wv * 16 + i][ln] = pack_bf16(f.x, f.y);   // pairs (4ln,4ln+1)   -> pair idx 2ln
    U[1][wv * 16 + i][ln] = pack_bf16(f.z, f.w);   // pairs (4ln+2,4ln+3) -> pair idx 2ln+1
  }
  __syncthreads();
  const int c_seg = (t & 7) * 8;
#pragma unroll
  for (int pass = 0; pass < 8; ++pass) {
    const int nl = pass * 32 + (t >> 3);
    const int p = nl >> 1;              // pair index
    const int h = p & 1, idx = p >> 1;  // SoA half, slot
    const uint sel = (nl & 1) ? 0x07060302u : 0x05040100u;
    uint o[4];
#pragma unroll
    for (int j = 0; j < 4; ++j) {
      uint ua = U[h][c_seg + 2 * j][idx];
      uint ub = U[h][c_seg + 2 * j + 1][idx];
      o[j] = __builtin_amdgcn_perm(ub, ua, sel);   // (bf(c_odd)<<16)|bf(c_even)
    }
    *(uint4*)(xT + ((size_t)b * 4096 + n0 + nl) * 512 + c0 + c_seg) = *(uint4*)o;
  }
}

// ---------------- kernel 3: fused q/k/v projection from xT ----------------
__global__ __launch_bounds__(256, 2) void k_proj(const ushort* __restrict__ xT,
                                                 const ushort* __restrict__ Wqb,
                                                 const ushort* __restrict__ Wkb,
                                                 const ushort* __restrict__ Wvb,
                                                 ushort* __restrict__ qb,
                                                 ushort* __restrict__ kb,
                                                 ushort* __restrict__ vb) {
  const int b = blockIdx.y, n0 = blockIdx.x * 64;
  const int lane = threadIdx.x & 63, w = threadIdx.x >> 6;
  const int quad = lane >> 4, l15 = lane & 15;
  const ushort* xT_b = xT + (size_t)b * 4096 * 512;

  const ushort* Wqk = (w < 2) ? (Wqb + (size_t)(w * 16 + l15) * 512)
                              : (Wkb + (size_t)((w - 2) * 16 + l15) * 512);

  f32x4 accv[8][4], accqk[4];
#pragma unroll
  for (int i = 0; i < 8; ++i)
#pragma unroll
    for (int nt = 0; nt < 4; ++nt) accv[i][nt] = {0.f, 0.f, 0.f, 0.f};
#pragma unroll
  for (int nt = 0; nt < 4; ++nt) accqk[nt] = {0.f, 0.f, 0.f, 0.f};

  for (int k0 = 0; k0 < 512; k0 += 32) {
    s16x8 bx[4];
#pragma unroll
    for (int nt = 0; nt < 4; ++nt)
      bx[nt] = *(const s16x8*)(xT_b + (size_t)(n0 + nt * 16 + l15) * 512 + k0 + quad * 8);
#pragma unroll
    for (int i = 0; i < 8; ++i) {
      s16x8 av = *(const s16x8*)(Wvb + (size_t)((8 * w + i) * 16 + l15) * 512 + k0 + quad * 8);
#pragma unroll
      for (int nt = 0; nt < 4; ++nt) accv[i][nt] = MFMA16(av, bx[nt], accv[i][nt]);
    }
    s16x8 aqk = *(const s16x8*)(Wqk + k0 + quad * 8);
#pragma unroll
    for (int nt = 0; nt < 4; ++nt) accqk[nt] = MFMA16(aqk, bx[nt], accqk[nt]);
  }

  ushort* vb_b = vb + (size_t)b * 512 * 4096;
#pragma unroll
  for (int i = 0; i < 8; ++i)
#pragma unroll
    for (int nt = 0; nt < 4; ++nt)
#pragma unroll
      for (int r = 0; r < 4; ++r)
        vb_b[(size_t)((8 * w + i) * 16 + quad * 4 + r) * 4096 + n0 + nt * 16 + l15] =
            f2bf(accv[i][nt][r]);

  ushort* qk_out = (w < 2) ? (qb + (size_t)b * 4096 * 32) : (kb + (size_t)b * 4096 * 32);
#pragma unroll
  for (int nt = 0; nt < 4; ++nt) {
    ushort4 u;
    u.x = f2bf(accqk[nt][0]); u.y = f2bf(accqk[nt][1]);
    u.z = f2bf(accqk[nt][2]); u.w = f2bf(accqk[nt][3]);
    *(ushort4*)(qk_out + (size_t)(n0 + nt * 16 + l15) * 32 + (w & 1) * 16 + quad * 4) = u;
  }
}

// ---------------- kernel 4: pass1 — Lneg[b][m] = -log2(sum_n 2^(S'[m,n])) ----------------
__global__ __launch_bounds__(256) void k_pass1(const ushort* __restrict__ qb,
                                               const ushort* __restrict__ kb,
                                               float* __restrict__ Lneg) {
  const int b = blockIdx.y, mt = blockIdx.x;
  const int lane = threadIdx.x & 63, w = threadIdx.x >> 6;
  const int quad = lane >> 4, l15 = lane & 15;
  const int m = mt * 64 + w * 16;
  const ushort* qb_b = qb + (size_t)b * 4096 * 32;
  const ushort* kb_b = kb + (size_t)b * 4096 * 32;
  const s16x8 aqf = *(const s16x8*)(qb_b + (size_t)(m + l15) * 32 + quad * 8);
  float ps[4] = {0.f, 0.f, 0.f, 0.f};
  const f32x4 zf = {0.f, 0.f, 0.f, 0.f};
  for (int n0 = 0; n0 < 4096; n0 += 64) {
#pragma unroll
    for (int nt = 0; nt < 4; ++nt) {
      s16x8 bk = *(const s16x8*)(kb_b + (size_t)(n0 + nt * 16 + l15) * 32 + quad * 8);
      f32x4 s = MFMA16(aqf, bk, zf);
#pragma unroll
      for (int r = 0; r < 4; ++r) ps[r] += fexp2(s[r]);
    }
  }
  for (int off = 1; off < 16; off <<= 1)
#pragma unroll
    for (int r = 0; r < 4; ++r) ps[r] += __shfl_xor(ps[r], off, 64);
  if (l15 == 0)
#pragma unroll
    for (int r = 0; r < 4; ++r)
      Lneg[(size_t)b * 4096 + m + quad * 4 + r] = -log2f(ps[r]);
}

// ---------------- kernel 5: pass2 — out = V @ 2^(S' + Lneg) ----------------
// Grid 512 = 8 b (XCD-aligned: blk&7) x 32 ntb x 2 cb. Block 4 waves (256 thr):
// tile 256c x 128n, chunk 64 m; 2 independent blocks/CU (c-split) -> phase skew
// without touching V reuse (n_tile stays 128; V[b] stays L2-resident).
// Each block produces the full 64m x 128n P (duplicated across the cb pair):
// wave w produces m-tiles {2*(w&1), 2*(w&1)+1} x n-tiles {4*(w>>1)..+3}.
// Per chunk: raw barrier (lgkm only) -> 8 P-reads (m0..31) -> produce x8
// (reg-only inputs) -> loadQ -> consume half1 (va0, rr issue per-nt) -> loadV0
// -> consume half2 (va1) -> loadV1.  Global prefetches in flight across barrier.
__global__ __launch_bounds__(256, 2) void k_pass2(const ushort* __restrict__ qb,
                                                  const ushort* __restrict__ kb,
                                                  const ushort* __restrict__ vb,
                                                  const float* __restrict__ Lneg,
                                                  float* __restrict__ out) {
  const int blk = blockIdx.x;
  const int b = blk & 7, blkb = blk >> 3;
  const int ntb = blkb & 31, cb = blkb >> 5;
  const int nbase = ntb * 128;
  const int lane = threadIdx.x & 63, w = threadIdx.x >> 6;   // 4 waves
  const int quad = lane >> 4, l15 = lane & 15;
  const int wm = w & 1, wn = w >> 1;
  const int cbase = cb * 256 + w * 64;
  const int swz = l15 & 7;

  __shared__ __align__(16) ushort PT[2][128 * 64];  // 32 KB; 16B-granule XOR swizzle

  const ushort* qb_b = qb + (size_t)b * 4096 * 32;
  const ushort* kb_b = kb + (size_t)b * 4096 * 32;
  const ushort* vb_b = vb + (size_t)b * 512 * 4096;
  const float* L_b = Lneg + (size_t)b * 4096;

  s16x8 kf[4];  // K rows for this wave's 4 produce n-tiles (T = 4*wn + i)
#pragma unroll
  for (int i = 0; i < 4; ++i)
    kf[i] = *(const s16x8*)(kb_b + (size_t)(nbase + (4 * wn + i) * 16 + l15) * 32 + quad * 8);

  f32x4 acc[4][8];  // [ci][nt]: 64c x 128n per wave
#pragma unroll
  for (int ci = 0; ci < 4; ++ci)
#pragma unroll
    for (int nt = 0; nt < 8; ++nt) acc[ci][nt] = {0.f, 0.f, 0.f, 0.f};

  s16x8 aqp[2];     // prefetched q A-frags for next produce (2 m-tiles)
  float4 l4p[2];    // prefetched Lneg
  s16x8 va0[4], va1[4];  // v A-frags: m0..31 / m32..63 of current chunk

  auto loadQ = [&](int chunk) {
    const int m0 = chunk * 64;
#pragma unroll
    for (int j = 0; j < 2; ++j) {
      const int M = 2 * wm + j;
      aqp[j] = *(const s16x8*)(qb_b + (size_t)(m0 + M * 16 + l15) * 32 + quad * 8);
      l4p[j] = *(const float4*)(L_b + m0 + M * 16 + quad * 4);
    }
  };
  auto loadV0 = [&](int chunk) {
    const int m0 = chunk * 64;
#pragma unroll
    for (int ci = 0; ci < 4; ++ci)
      va0[ci] = *(const s16x8*)(vb_b + (size_t)(cbase + ci * 16 + l15) * 4096 + m0 + quad * 8);
  };
  auto loadV1 = [&](int chunk) {
    const int m0 = chunk * 64;
#pragma unroll
    for (int ci = 0; ci < 4; ++ci)
      va1[ci] = *(const s16x8*)(vb_b + (size_t)(cbase + ci * 16 + l15) * 4096 + m0 + 32 + quad * 8);
  };
  // one produce tile: QK MFMA (Lneg as C-in) -> exp2 -> pack -> ds_write.
  // Wave w produces m-tile M = 2*wm+j, n-tile T = 4*wn+i.
  auto produce_tile = [&](int buf, int j, int i) {
    char* Pw = (char*)&PT[buf][0];
    const int M = 2 * wm + j;
    const int T = 4 * wn + i;
    f32x4 cin; cin.x = l4p[j].x; cin.y = l4p[j].y; cin.z = l4p[j].z; cin.w = l4p[j].w;
    f32x4 s = MFMA16(aqp[j], kf[i], cin);            // S' + Lneg  (<= ~0)
    uint2 u;
    u.x = pack_bf16(fexp2(s.x), fexp2(s.y));
    u.y = pack_bf16(fexp2(s.z), fexp2(s.w));
    const int row = T * 16 + l15;
    const int gran = (2 * M + (quad >> 1)) ^ swz;
    *(uint2*)(Pw + row * 128 + gran * 16 + (quad & 1) * 8) = u;
  };

  loadQ(0);
#pragma unroll
  for (int j = 0; j < 2; ++j)
#pragma unroll
    for (int i = 0; i < 4; ++i) produce_tile(0, j, i);   // prologue: produce chunk 0
  loadQ(1);
  loadV0(0);
  loadV1(0);

  for (int chunk = 0; chunk < 64; ++chunk) {
    const int buf = chunk & 1;
    chunk_barrier();   // lgkm drain + s_barrier; global prefetches stay in flight
    const char* P = (const char*)&PT[buf][0];
    // --- issue all half1 P reads (m0..31, nt 0..7) ---
    s16x8 pg[8];
#pragma unroll
    for (int nt = 0; nt < 8; ++nt)
      pg[nt] = *(const s16x8*)(P + (nt * 16 + l15) * 128 + (quad ^ swz) * 16);
    // --- produce chunk+1 into buf^1: register-only inputs, no dep on pg ---
    // (chunk 63's produce reuses aqp(63) and writes a never-read buffer: safe.)
#pragma unroll
    for (int j = 0; j < 2; ++j)
#pragma unroll
      for (int i = 0; i < 4; ++i) produce_tile(buf ^ 1, j, i);
    if (chunk < 62) loadQ(chunk + 2);   // after produce (produce consumed aqp)
    // --- consume half1 (va0, m0..31); interleave rr issue per nt ---
    s16x8 rr[8];
#pragma unroll
    for (int nt = 0; nt < 8; ++nt) {
#pragma unroll
      for (int ci = 0; ci < 4; ++ci) acc[ci][nt] = MFMA16(va0[ci], pg[nt], acc[ci][nt]);
      rr[nt] = *(const s16x8*)(P + (nt * 16 + l15) * 128 + ((4 + quad) ^ swz) * 16);
    }
    // --- va0 dead: prefetch next chunk's va0 (L2 latency hides under half2) ---
    if (chunk < 63) loadV0(chunk + 1);
    // --- consume half2 (va1, m32..63) ---
#pragma unroll
    for (int nt = 0; nt < 8; ++nt)
#pragma unroll
      for (int ci = 0; ci < 4; ++ci) acc[ci][nt] = MFMA16(va1[ci], rr[nt], acc[ci][nt]);
    // --- prefetch next chunk's va1 ---
    if (chunk < 63) loadV1(chunk + 1);
  }

  float* out_b = out + (size_t)b * 512 * 4096;
#pragma unroll
  for (int ci = 0; ci < 4; ++ci)
#pragma unroll
    for (int nt = 0; nt < 8; ++nt) {
      const int n = nbase + nt * 16 + l15;
      const int c0 = cbase + ci * 16 + quad * 4;
#pragma unroll
      for (int r = 0; r < 4; ++r) out_b[(size_t)(c0 + r) * 4096 + n] = acc[ci][nt][r];
    }
}

// ---------------- launch ----------------
extern "C" void kernel_launch(void* const* d_in, const int* in_sizes, int n_in,
                              void* d_out, int out_size, void* d_ws, size_t ws_size,
                              hipStream_t stream) {
  const float* x  = (const float*)d_in[0];   // [8,512,64,64]
  const float* Wq = (const float*)d_in[1];   // [32,512]
  const float* Wk = (const float*)d_in[2];   // [32,512]
  const float* Wv = (const float*)d_in[3];   // [512,512]
  float* out = (float*)d_out;                // [8,512,64,64]

  char* ws = (char*)d_ws;
  ushort* vb  = (ushort*)(ws + 0);           // 33,554,432 B
  ushort* xT  = (ushort*)(ws + 33554432);    // 33,554,432 B
  ushort* qb  = (ushort*)(ws + 67108864);    //  2,097,152 B
  ushort* kb  = (ushort*)(ws + 69206016);    //  2,097,152 B
  ushort* Wvb = (ushort*)(ws + 71303168);    //    524,288 B
  ushort* Wqb = (ushort*)(ws + 71827456);    //     32,768 B
  ushort* Wkb = (ushort*)(ws + 71860224);    //     32,768 B
  float*  Lrs = (float*)(ws + 71892992);     //    131,072 B  (total 72,024,064)

  hipLaunchKernelGGL(k_cvt_w, dim3(1152), dim3(256), 0, stream, Wq, Wk, Wv, Wqb, Wkb, Wvb);
  hipLaunchKernelGGL(k_xpose, dim3(16, 8, 8), dim3(256), 0, stream, x, xT);
  hipLaunchKernelGGL(k_proj, dim3(64, 8), dim3(256), 0, stream, xT, Wqb, Wkb, Wvb, qb, kb, vb);
  hipLaunchKernelGGL(k_pass1, dim3(64, 8), dim3(256), 0, stream, qb, kb, Lrs);
  hipLaunchKernelGGL(k_pass2, dim3(512), dim3(256), 0, stream, qb, kb, vb, Lrs, out);
}

// Round 9
// 341.737 us; speedup vs baseline: 1.3715x; 1.0469x over previous
//
#include <hip/hip_runtime.h>
#include <hip/hip_bf16.h>

// SelfAttention non-local block: B=8, C=512, N=4096, CQK=32.  All-MFMA bf16 path.
// v11 = v8 + T5 setprio around consume MFMA clusters:
//  - v10 refuted the lockstep theory (2 independent blocks/CU: no skew gain,
//    dup-produce cost 17us). v8 remains best (163.5us pass2). Residual gap
//    (6130 cyc/chunk vs 2640 MFMA) is intra-wave serial chain; co-resident
//    waves drift into the same phase and round-robin issue slots.
//  - s_setprio(1) around consume (pure-MFMA phase), prio 0 for produce/loads:
//    lets an MFMA-phase wave win arbitration over a produce/LDS-phase wave
//    (T5, +21-39% on phase-split GEMM m218b/m224; null only on pure lockstep).
//  - everything else identical to v8 for clean A/B.
// ws: vb 33.5MB | xT 33.5MB | qb 2MB | kb 2MB | Wvb 512KB | Wqb 32KB | Wkb 32KB | Lneg 128KB

typedef __attribute__((ext_vector_type(8))) short s16x8;
typedef __attribute__((ext_vector_type(4))) float f32x4;

#define MFMA16(a, b, c) __builtin_amdgcn_mfma_f32_16x16x32_bf16((a), (b), (c), 0, 0, 0)

__device__ __forceinline__ ushort f2bf(float f) {
  union { float f; unsigned u; } v; v.f = f;
  return (ushort)((v.u + 0x8000u) >> 16);
}
__device__ __forceinline__ unsigned pack_bf16(float lo, float hi) {  // (hi<<16)|lo
  union { float f; unsigned u; } a, b; a.f = lo; b.f = hi;
  return __builtin_amdgcn_perm(b.u + 0x8000u, a.u + 0x8000u, 0x07060302u);
}
__device__ __forceinline__ float fexp2(float x) { return __builtin_amdgcn_exp2f(x); }

// Raw chunk barrier: publish DS writes, sync, but leave global loads in flight.
__device__ __forceinline__ void chunk_barrier() {
  asm volatile("s_waitcnt lgkmcnt(0)" ::: "memory");
  __builtin_amdgcn_s_barrier();
  __builtin_amdgcn_sched_barrier(0);
}

// ---------------- kernel 1: weights -> bf16 (Wq pre-scaled by log2e) ----------------
__global__ void k_cvt_w(const float* __restrict__ Wq, const float* __restrict__ Wk,
                        const float* __restrict__ Wv, ushort* __restrict__ Wqb,
                        ushort* __restrict__ Wkb, ushort* __restrict__ Wvb) {
  int i = blockIdx.x * 256 + threadIdx.x;
  if (i < 262144) Wvb[i] = f2bf(Wv[i]);
  else if (i < 278528) Wqb[i - 262144] = f2bf(Wq[i - 262144] * 1.4426950408889634f);
  else if (i < 294912) Wkb[i - 278528] = f2bf(Wk[i - 278528]);
}

// ---------------- kernel 2: transpose x -> xT bf16 ----------------
// Tile 64c x 256n. Phase1: float4 row loads (1KB contiguous per row), pack n-pairs,
// SoA LDS U[2][64][65] (even/odd pair split => <=2-way banks). Phase2: 8-lane groups
// build 128B-contiguous xT rows via v_perm extraction.
__global__ __launch_bounds__(256) void k_xpose(const float* __restrict__ x,
                                               ushort* __restrict__ xT) {
  const int b = blockIdx.z, c0 = blockIdx.y * 64, n0 = blockIdx.x * 256;
  __shared__ uint U[2][64][65];
  const int t = threadIdx.x;
  const int wv = t >> 6, ln = t & 63;
  const float* xp = x + ((size_t)b * 512 + c0 + wv * 16) * 4096 + n0 + ln * 4;
#pragma unroll
  for (int i = 0; i < 16; ++i) {
    float4 f = *(const float4*)(xp + (size_t)i * 4096);
    U[0][wv * 16 + i][ln] = pack_bf16(f.x, f.y);   // pairs (4ln,4ln+1)   -> pair idx 2ln
    U[1][wv * 16 + i][ln] = pack_bf16(f.z, f.w);   // pairs (4ln+2,4ln+3) -> pair idx 2ln+1
  }
  __syncthreads();
  const int c_seg = (t & 7) * 8;
#pragma unroll
  for (int pass = 0; pass < 8; ++pass) {
    const int nl = pass * 32 + (t >> 3);
    const int p = nl >> 1;              // pair index
    const int h = p & 1, idx = p >> 1;  // SoA half, slot
    const uint sel = (nl & 1) ? 0x07060302u : 0x05040100u;
    uint o[4];
#pragma unroll
    for (int j = 0; j < 4; ++j) {
      uint ua = U[h][c_seg + 2 * j][idx];
      uint ub = U[h][c_seg + 2 * j + 1][idx];
      o[j] = __builtin_amdgcn_perm(ub, ua, sel);   // (bf(c_odd)<<16)|bf(c_even)
    }
    *(uint4*)(xT + ((size_t)b * 4096 + n0 + nl) * 512 + c0 + c_seg) = *(uint4*)o;
  }
}

// ---------------- kernel 3: fused q/k/v projection from xT ----------------
__global__ __launch_bounds__(256, 2) void k_proj(const ushort* __restrict__ xT,
                                                 const ushort* __restrict__ Wqb,
                                                 const ushort* __restrict__ Wkb,
                                                 const ushort* __restrict__ Wvb,
                                                 ushort* __restrict__ qb,
                                                 ushort* __restrict__ kb,
                                                 ushort* __restrict__ vb) {
  const int b = blockIdx.y, n0 = blockIdx.x * 64;
  const int lane = threadIdx.x & 63, w = threadIdx.x >> 6;
  const int quad = lane >> 4, l15 = lane & 15;
  const ushort* xT_b = xT + (size_t)b * 4096 * 512;

  const ushort* Wqk = (w < 2) ? (Wqb + (size_t)(w * 16 + l15) * 512)
                              : (Wkb + (size_t)((w - 2) * 16 + l15) * 512);

  f32x4 accv[8][4], accqk[4];
#pragma unroll
  for (int i = 0; i < 8; ++i)
#pragma unroll
    for (int nt = 0; nt < 4; ++nt) accv[i][nt] = {0.f, 0.f, 0.f, 0.f};
#pragma unroll
  for (int nt = 0; nt < 4; ++nt) accqk[nt] = {0.f, 0.f, 0.f, 0.f};

  for (int k0 = 0; k0 < 512; k0 += 32) {
    s16x8 bx[4];
#pragma unroll
    for (int nt = 0; nt < 4; ++nt)
      bx[nt] = *(const s16x8*)(xT_b + (size_t)(n0 + nt * 16 + l15) * 512 + k0 + quad * 8);
#pragma unroll
    for (int i = 0; i < 8; ++i) {
      s16x8 av = *(const s16x8*)(Wvb + (size_t)((8 * w + i) * 16 + l15) * 512 + k0 + quad * 8);
#pragma unroll
      for (int nt = 0; nt < 4; ++nt) accv[i][nt] = MFMA16(av, bx[nt], accv[i][nt]);
    }
    s16x8 aqk = *(const s16x8*)(Wqk + k0 + quad * 8);
#pragma unroll
    for (int nt = 0; nt < 4; ++nt) accqk[nt] = MFMA16(aqk, bx[nt], accqk[nt]);
  }

  ushort* vb_b = vb + (size_t)b * 512 * 4096;
#pragma unroll
  for (int i = 0; i < 8; ++i)
#pragma unroll
    for (int nt = 0; nt < 4; ++nt)
#pragma unroll
      for (int r = 0; r < 4; ++r)
        vb_b[(size_t)((8 * w + i) * 16 + quad * 4 + r) * 4096 + n0 + nt * 16 + l15] =
            f2bf(accv[i][nt][r]);

  ushort* qk_out = (w < 2) ? (qb + (size_t)b * 4096 * 32) : (kb + (size_t)b * 4096 * 32);
#pragma unroll
  for (int nt = 0; nt < 4; ++nt) {
    ushort4 u;
    u.x = f2bf(accqk[nt][0]); u.y = f2bf(accqk[nt][1]);
    u.z = f2bf(accqk[nt][2]); u.w = f2bf(accqk[nt][3]);
    *(ushort4*)(qk_out + (size_t)(n0 + nt * 16 + l15) * 32 + (w & 1) * 16 + quad * 4) = u;
  }
}

// ---------------- kernel 4: pass1 — Lneg[b][m] = -log2(sum_n 2^(S'[m,n])) ----------------
__global__ __launch_bounds__(256) void k_pass1(const ushort* __restrict__ qb,
                                               const ushort* __restrict__ kb,
                                               float* __restrict__ Lneg) {
  const int b = blockIdx.y, mt = blockIdx.x;
  const int lane = threadIdx.x & 63, w = threadIdx.x >> 6;
  const int quad = lane >> 4, l15 = lane & 15;
  const int m = mt * 64 + w * 16;
  const ushort* qb_b = qb + (size_t)b * 4096 * 32;
  const ushort* kb_b = kb + (size_t)b * 4096 * 32;
  const s16x8 aqf = *(const s16x8*)(qb_b + (size_t)(m + l15) * 32 + quad * 8);
  float ps[4] = {0.f, 0.f, 0.f, 0.f};
  const f32x4 zf = {0.f, 0.f, 0.f, 0.f};
  for (int n0 = 0; n0 < 4096; n0 += 64) {
#pragma unroll
    for (int nt = 0; nt < 4; ++nt) {
      s16x8 bk = *(const s16x8*)(kb_b + (size_t)(n0 + nt * 16 + l15) * 32 + quad * 8);
      f32x4 s = MFMA16(aqf, bk, zf);
#pragma unroll
      for (int r = 0; r < 4; ++r) ps[r] += fexp2(s[r]);
    }
  }
  for (int off = 1; off < 16; off <<= 1)
#pragma unroll
    for (int r = 0; r < 4; ++r) ps[r] += __shfl_xor(ps[r], off, 64);
  if (l15 == 0)
#pragma unroll
    for (int r = 0; r < 4; ++r)
      Lneg[(size_t)b * 4096 + m + quad * 4 + r] = -log2f(ps[r]);
}

// ---------------- kernel 5: pass2 — out = V @ 2^(S' + Lneg) ----------------
// Grid 256 = 8 b (XCD-aligned: blk&7) x 32 ntb. Block 8 waves (512 thr): tile
// 512c x 128n, chunk 64 m. Per chunk: raw barrier (lgkm only) -> issue 8 P-reads
// (m0..31) -> produce x4 (reg-only inputs; hides the LDS burst) -> loadQ ->
// [prio1] consume half1 (va0, rr issue per-nt) [prio0] -> loadV0 -> [prio1]
// consume half2 (va1) [prio0] -> loadV1.  Global prefetches in flight across
// the barrier; consume runs at wave priority 1 (T5).
__global__ __launch_bounds__(512, 2) void k_pass2(const ushort* __restrict__ qb,
                                                  const ushort* __restrict__ kb,
                                                  const ushort* __restrict__ vb,
                                                  const float* __restrict__ Lneg,
                                                  float* __restrict__ out) {
  const int blk = blockIdx.x;
  const int b = blk & 7, ntb = blk >> 3;
  const int nbase = ntb * 128;
  const int lane = threadIdx.x & 63, w = threadIdx.x >> 6;   // 8 waves
  const int quad = lane >> 4, l15 = lane & 15;
  const int cbase = w * 64;
  const int swz = l15 & 7;
  const int Mw = w >> 1;               // produce m-tile (0..3)
  const int Tb = (w & 1) * 4;          // produce n-tile base (0 or 4)

  __shared__ __align__(16) ushort PT[2][128 * 64];  // 32 KB; 16B-granule XOR swizzle

  const ushort* qb_b = qb + (size_t)b * 4096 * 32;
  const ushort* kb_b = kb + (size_t)b * 4096 * 32;
  const ushort* vb_b = vb + (size_t)b * 512 * 4096;
  const float* L_b = Lneg + (size_t)b * 4096;

  s16x8 kf[4];  // K rows for this wave's 4 produce n-tiles
#pragma unroll
  for (int i = 0; i < 4; ++i)
    kf[i] = *(const s16x8*)(kb_b + (size_t)(nbase + (Tb + i) * 16 + l15) * 32 + quad * 8);

  f32x4 acc[4][8];
#pragma unroll
  for (int ci = 0; ci < 4; ++ci)
#pragma unroll
    for (int nt = 0; nt < 8; ++nt) acc[ci][nt] = {0.f, 0.f, 0.f, 0.f};

  s16x8 aqp;        // prefetched q A-frag for next produce (single m-tile)
  float4 l4p;       // prefetched Lneg
  s16x8 va0[4], va1[4];  // v A-frags: m0..31 / m32..63 of current chunk

  auto loadQ = [&](int chunk) {
    const int m0 = chunk * 64;
    aqp = *(const s16x8*)(qb_b + (size_t)(m0 + Mw * 16 + l15) * 32 + quad * 8);
    l4p = *(const float4*)(L_b + m0 + Mw * 16 + quad * 4);
  };
  auto loadV0 = [&](int chunk) {
    const int m0 = chunk * 64;
#pragma unroll
    for (int ci = 0; ci < 4; ++ci)
      va0[ci] = *(const s16x8*)(vb_b + (size_t)(cbase + ci * 16 + l15) * 4096 + m0 + quad * 8);
  };
  auto loadV1 = [&](int chunk) {
    const int m0 = chunk * 64;
#pragma unroll
    for (int ci = 0; ci < 4; ++ci)
      va1[ci] = *(const s16x8*)(vb_b + (size_t)(cbase + ci * 16 + l15) * 4096 + m0 + 32 + quad * 8);
  };
  // one produce tile: QK MFMA (Lneg as C-in) -> exp2 -> pack -> ds_write.
  auto produce_tile = [&](int buf, int i) {
    char* Pw = (char*)&PT[buf][0];
    const int T = Tb + i;
    f32x4 cin; cin.x = l4p.x; cin.y = l4p.y; cin.z = l4p.z; cin.w = l4p.w;
    f32x4 s = MFMA16(aqp, kf[i], cin);               // S' + Lneg  (<= ~0)
    uint2 u;
    u.x = pack_bf16(fexp2(s.x), fexp2(s.y));
    u.y = pack_bf16(fexp2(s.z), fexp2(s.w));
    const int row = T * 16 + l15;
    const int gran = (2 * Mw + (quad >> 1)) ^ swz;
    *(uint2*)(Pw + row * 128 + gran * 16 + (quad & 1) * 8) = u;
  };

  loadQ(0);
#pragma unroll
  for (int i = 0; i < 4; ++i) produce_tile(0, i);    // prologue: produce chunk 0
  loadQ(1);
  loadV0(0);
  loadV1(0);

  for (int chunk = 0; chunk < 64; ++chunk) {
    const int buf = chunk & 1;
    chunk_barrier();   // lgkm drain + s_barrier; global prefetches stay in flight
    const char* P = (const char*)&PT[buf][0];
    // --- issue all half1 P reads (m0..31, nt 0..7) ---
    s16x8 pg[8];
#pragma unroll
    for (int nt = 0; nt < 8; ++nt)
      pg[nt] = *(const s16x8*)(P + (nt * 16 + l15) * 128 + (quad ^ swz) * 16);
    // --- produce chunk+1 into buf^1: register-only inputs, no dep on pg ---
    // (chunk 63's produce reuses aqp(63) and writes a never-read buffer: safe.)
#pragma unroll
    for (int i = 0; i < 4; ++i) produce_tile(buf ^ 1, i);
    if (chunk < 62) loadQ(chunk + 2);   // after produce (produce consumed aqp)
    // --- consume half1 (va0, m0..31) at prio 1; interleave rr issue per nt ---
    __builtin_amdgcn_s_setprio(1);
    s16x8 rr[8];
#pragma unroll
    for (int nt = 0; nt < 8; ++nt) {
#pragma unroll
      for (int ci = 0; ci < 4; ++ci) acc[ci][nt] = MFMA16(va0[ci], pg[nt], acc[ci][nt]);
      rr[nt] = *(const s16x8*)(P + (nt * 16 + l15) * 128 + ((4 + quad) ^ swz) * 16);
    }
    __builtin_amdgcn_s_setprio(0);
    // --- va0 dead: prefetch next chunk's va0 (L2 latency hides under half2) ---
    if (chunk < 63) loadV0(chunk + 1);
    // --- consume half2 (va1, m32..63) at prio 1 ---
    __builtin_amdgcn_s_setprio(1);
#pragma unroll
    for (int nt = 0; nt < 8; ++nt)
#pragma unroll
      for (int ci = 0; ci < 4; ++ci) acc[ci][nt] = MFMA16(va1[ci], rr[nt], acc[ci][nt]);
    __builtin_amdgcn_s_setprio(0);
    // --- prefetch next chunk's va1 ---
    if (chunk < 63) loadV1(chunk + 1);
  }

  float* out_b = out + (size_t)b * 512 * 4096;
#pragma unroll
  for (int ci = 0; ci < 4; ++ci)
#pragma unroll
    for (int nt = 0; nt < 8; ++nt) {
      const int n = nbase + nt * 16 + l15;
      const int c0 = cbase + ci * 16 + quad * 4;
#pragma unroll
      for (int r = 0; r < 4; ++r) out_b[(size_t)(c0 + r) * 4096 + n] = acc[ci][nt][r];
    }
}

// ---------------- launch ----------------
extern "C" void kernel_launch(void* const* d_in, const int* in_sizes, int n_in,
                              void* d_out, int out_size, void* d_ws, size_t ws_size,
                              hipStream_t stream) {
  const float* x  = (const float*)d_in[0];   // [8,512,64,64]
  const float* Wq = (const float*)d_in[1];   // [32,512]
  const float* Wk = (const float*)d_in[2];   // [32,512]
  const float* Wv = (const float*)d_in[3];   // [512,512]
  float* out = (float*)d_out;                // [8,512,64,64]

  char* ws = (char*)d_ws;
  ushort* vb  = (ushort*)(ws + 0);           // 33,554,432 B
  ushort* xT  = (ushort*)(ws + 33554432);    // 33,554,432 B
  ushort* qb  = (ushort*)(ws + 67108864);    //  2,097,152 B
  ushort* kb  = (ushort*)(ws + 69206016);    //  2,097,152 B
  ushort* Wvb = (ushort*)(ws + 71303168);    //    524,288 B
  ushort* Wqb = (ushort*)(ws + 71827456);    //     32,768 B
  ushort* Wkb = (ushort*)(ws + 71860224);    //     32,768 B
  float*  Lrs = (float*)(ws + 71892992);     //    131,072 B  (total 72,024,064)

  hipLaunchKernelGGL(k_cvt_w, dim3(1152), dim3(256), 0, stream, Wq, Wk, Wv, Wqb, Wkb, Wvb);
  hipLaunchKernelGGL(k_xpose, dim3(16, 8, 8), dim3(256), 0, stream, x, xT);
  hipLaunchKernelGGL(k_proj, dim3(64, 8), dim3(256), 0, stream, xT, Wqb, Wkb, Wvb, qb, kb, vb);
  hipLaunchKernelGGL(k_pass1, dim3(64, 8), dim3(256), 0, stream, qb, kb, Lrs);
  hipLaunchKernelGGL(k_pass2, dim3(256), dim3(512), 0, stream, qb, kb, vb, Lrs, out);
}

// Round 10
// 322.534 us; speedup vs baseline: 1.4532x; 1.0595x over previous
//
#include <hip/hip_runtime.h>
#include <hip/hip_bf16.h>

// SelfAttention non-local block: B=8, C=512, N=4096, CQK=32.  All-MFMA bf16 path.
// v12 = v11 pass2 (frozen) + xpose fused into proj:
//  - k_xpose deleted. xT (33.5MB global) existed only to give proj coalesced
//    B-frags; that cost 96 MB of HBM round-trip + a launch (~25-35us), plus
//    proj's k-loop chained on global b128 gathers.
//  - k_proj now stages its 512c x 64n x-tile in LDS: XB[64 n][512 c] bf16
//    (64 KB) with 16B-granule XOR swizzle by n&7 (b128 reads spread 8 lanes
//    per bank-group -> conflict-free). Built in 16 sub-tiles of 32c via the
//    proven pair-pack + v_perm transpose (U = 4.25 KB). Total LDS 70 KB ->
//    2 blocks/CU kept. K-loop bx = swizzled ds_read_b128 (no L2 latency).
//  - pass2 identical to v11 (setprio consume, raw lgkm-only chunk barrier).
// ws: vb 33.5MB | qb 2MB | kb 2MB | Wvb 512KB | Wqb 32KB | Wkb 32KB | Lneg 128KB

typedef __attribute__((ext_vector_type(8))) short s16x8;
typedef __attribute__((ext_vector_type(4))) float f32x4;

#define MFMA16(a, b, c) __builtin_amdgcn_mfma_f32_16x16x32_bf16((a), (b), (c), 0, 0, 0)

__device__ __forceinline__ ushort f2bf(float f) {
  union { float f; unsigned u; } v; v.f = f;
  return (ushort)((v.u + 0x8000u) >> 16);
}
__device__ __forceinline__ unsigned pack_bf16(float lo, float hi) {  // (hi<<16)|lo
  union { float f; unsigned u; } a, b; a.f = lo; b.f = hi;
  return __builtin_amdgcn_perm(b.u + 0x8000u, a.u + 0x8000u, 0x07060302u);
}
__device__ __forceinline__ float fexp2(float x) { return __builtin_amdgcn_exp2f(x); }

// Raw chunk barrier: publish DS writes, sync, but leave global loads in flight.
__device__ __forceinline__ void chunk_barrier() {
  asm volatile("s_waitcnt lgkmcnt(0)" ::: "memory");
  __builtin_amdgcn_s_barrier();
  __builtin_amdgcn_sched_barrier(0);
}

// ---------------- kernel 1: weights -> bf16 (Wq pre-scaled by log2e) ----------------
__global__ void k_cvt_w(const float* __restrict__ Wq, const float* __restrict__ Wk,
                        const float* __restrict__ Wv, ushort* __restrict__ Wqb,
                        ushort* __restrict__ Wkb, ushort* __restrict__ Wvb) {
  int i = blockIdx.x * 256 + threadIdx.x;
  if (i < 262144) Wvb[i] = f2bf(Wv[i]);
  else if (i < 278528) Wqb[i - 262144] = f2bf(Wq[i - 262144] * 1.4426950408889634f);
  else if (i < 294912) Wkb[i - 278528] = f2bf(Wk[i - 278528]);
}

// ---------------- kernel 2: fused transpose + q/k/v projection ----------------
// Grid (64 ntb, 8 b), 256 thr, 2 blocks/CU. Prologue: stage x[b][0..512c][n0..+64n]
// into XB[64 n][512 c] bf16 (XOR-swizzled granules), 16 sub-tiles of 32 c:
//   phase1: 512 coalesced float4 row loads -> pair-packed U[2][32][17]
//   phase2: v_perm extraction -> 256 uint4 (8 c per n) -> swizzled XB rows
// K-loop: bx frags via swizzled ds_read_b128; A-frags (weights) from global (L2).
__global__ __launch_bounds__(256, 2) void k_proj(const float* __restrict__ x,
                                                 const ushort* __restrict__ Wqb,
                                                 const ushort* __restrict__ Wkb,
                                                 const ushort* __restrict__ Wvb,
                                                 ushort* __restrict__ qb,
                                                 ushort* __restrict__ kb,
                                                 ushort* __restrict__ vb) {
  const int b = blockIdx.y, n0 = blockIdx.x * 64;
  const int t = threadIdx.x;
  const int lane = t & 63, w = t >> 6;
  const int quad = lane >> 4, l15 = lane & 15;

  __shared__ __align__(16) ushort XB[64 * 512];  // [n][c] bf16, granule-swizzled; 64 KB
  __shared__ uint U[2][32][17];                  // pair-packed staging; 4.25 KB

  const float* x_b = x + (size_t)b * 512 * 4096;

  // ---- stage + transpose x-tile into XB ----
  for (int s = 0; s < 16; ++s) {
    const int c0s = s * 32;
    // phase1: 32 rows x 64 n as 512 float4s (coalesced), pack n-pairs into U
#pragma unroll
    for (int k = 0; k < 2; ++k) {
      const int idx = t + k * 256;          // 0..511
      const int cr = idx >> 4, c4 = idx & 15;
      float4 f = *(const float4*)(x_b + (size_t)(c0s + cr) * 4096 + n0 + c4 * 4);
      U[0][cr][c4] = pack_bf16(f.x, f.y);   // n = 4c4, 4c4+1
      U[1][cr][c4] = pack_bf16(f.z, f.w);   // n = 4c4+2, 4c4+3
    }
    __syncthreads();
    // phase2: thread -> (n = t&63, granule gl = t>>6): build 16B of 8 consecutive c
    {
      const int n = t & 63, gl = t >> 6;
      const int h = (n >> 1) & 1, c4 = n >> 2;
      const uint sel = (n & 1) ? 0x07060302u : 0x05040100u;
      uint o[4];
#pragma unroll
      for (int j = 0; j < 4; ++j) {
        uint ua = U[h][gl * 8 + 2 * j][c4];      // even c of pair
        uint ub = U[h][gl * 8 + 2 * j + 1][c4];  // odd c
        o[j] = __builtin_amdgcn_perm(ub, ua, sel);  // (bf(c_odd)<<16)|bf(c_even)
      }
      const int gfull = (c0s >> 3) + gl;           // granule index 0..63
      const int gsw = gfull ^ (n & 7);             // XOR swizzle (low 3 bits)
      *(uint4*)((char*)XB + n * 1024 + gsw * 16) = *(uint4*)o;
    }
    __syncthreads();
  }

  // ---- MFMA K-loop (B-frags from XB) ----
  const ushort* Wqk = (w < 2) ? (Wqb + (size_t)(w * 16 + l15) * 512)
                              : (Wkb + (size_t)((w - 2) * 16 + l15) * 512);

  f32x4 accv[8][4], accqk[4];
#pragma unroll
  for (int i = 0; i < 8; ++i)
#pragma unroll
    for (int nt = 0; nt < 4; ++nt) accv[i][nt] = {0.f, 0.f, 0.f, 0.f};
#pragma unroll
  for (int nt = 0; nt < 4; ++nt) accqk[nt] = {0.f, 0.f, 0.f, 0.f};

  const char* XBb = (const char*)XB;
  for (int k0 = 0; k0 < 512; k0 += 32) {
    s16x8 bx[4];
#pragma unroll
    for (int nt = 0; nt < 4; ++nt) {
      const int nl = nt * 16 + l15;
      bx[nt] = *(const s16x8*)(XBb + nl * 1024 + ((((k0 >> 3) + quad) ^ (nl & 7)) << 4));
    }
#pragma unroll
    for (int i = 0; i < 8; ++i) {
      s16x8 av = *(const s16x8*)(Wvb + (size_t)((8 * w + i) * 16 + l15) * 512 + k0 + quad * 8);
#pragma unroll
      for (int nt = 0; nt < 4; ++nt) accv[i][nt] = MFMA16(av, bx[nt], accv[i][nt]);
    }
    s16x8 aqk = *(const s16x8*)(Wqk + k0 + quad * 8);
#pragma unroll
    for (int nt = 0; nt < 4; ++nt) accqk[nt] = MFMA16(aqk, bx[nt], accqk[nt]);
  }

  ushort* vb_b = vb + (size_t)b * 512 * 4096;
#pragma unroll
  for (int i = 0; i < 8; ++i)
#pragma unroll
    for (int nt = 0; nt < 4; ++nt)
#pragma unroll
      for (int r = 0; r < 4; ++r)
        vb_b[(size_t)((8 * w + i) * 16 + quad * 4 + r) * 4096 + n0 + nt * 16 + l15] =
            f2bf(accv[i][nt][r]);

  ushort* qk_out = (w < 2) ? (qb + (size_t)b * 4096 * 32) : (kb + (size_t)b * 4096 * 32);
#pragma unroll
  for (int nt = 0; nt < 4; ++nt) {
    ushort4 u;
    u.x = f2bf(accqk[nt][0]); u.y = f2bf(accqk[nt][1]);
    u.z = f2bf(accqk[nt][2]); u.w = f2bf(accqk[nt][3]);
    *(ushort4*)(qk_out + (size_t)(n0 + nt * 16 + l15) * 32 + (w & 1) * 16 + quad * 4) = u;
  }
}

// ---------------- kernel 3: pass1 — Lneg[b][m] = -log2(sum_n 2^(S'[m,n])) ----------------
__global__ __launch_bounds__(256) void k_pass1(const ushort* __restrict__ qb,
                                               const ushort* __restrict__ kb,
                                               float* __restrict__ Lneg) {
  const int b = blockIdx.y, mt = blockIdx.x;
  const int lane = threadIdx.x & 63, w = threadIdx.x >> 6;
  const int quad = lane >> 4, l15 = lane & 15;
  const int m = mt * 64 + w * 16;
  const ushort* qb_b = qb + (size_t)b * 4096 * 32;
  const ushort* kb_b = kb + (size_t)b * 4096 * 32;
  const s16x8 aqf = *(const s16x8*)(qb_b + (size_t)(m + l15) * 32 + quad * 8);
  float ps[4] = {0.f, 0.f, 0.f, 0.f};
  const f32x4 zf = {0.f, 0.f, 0.f, 0.f};
  for (int n0 = 0; n0 < 4096; n0 += 64) {
#pragma unroll
    for (int nt = 0; nt < 4; ++nt) {
      s16x8 bk = *(const s16x8*)(kb_b + (size_t)(n0 + nt * 16 + l15) * 32 + quad * 8);
      f32x4 s = MFMA16(aqf, bk, zf);
#pragma unroll
      for (int r = 0; r < 4; ++r) ps[r] += fexp2(s[r]);
    }
  }
  for (int off = 1; off < 16; off <<= 1)
#pragma unroll
    for (int r = 0; r < 4; ++r) ps[r] += __shfl_xor(ps[r], off, 64);
  if (l15 == 0)
#pragma unroll
    for (int r = 0; r < 4; ++r)
      Lneg[(size_t)b * 4096 + m + quad * 4 + r] = -log2f(ps[r]);
}

// ---------------- kernel 4: pass2 — out = V @ 2^(S' + Lneg) ----------------
// Grid 256 = 8 b (XCD-aligned: blk&7) x 32 ntb. Block 8 waves (512 thr): tile
// 512c x 128n, chunk 64 m. Per chunk: raw barrier (lgkm only) -> issue 8 P-reads
// (m0..31) -> produce x4 (reg-only inputs) -> loadQ -> [prio1] consume half1
// (va0, rr issue per-nt) [prio0] -> loadV0 -> [prio1] consume half2 (va1)
// [prio0] -> loadV1.  Global prefetches in flight across the barrier.
__global__ __launch_bounds__(512, 2) void k_pass2(const ushort* __restrict__ qb,
                                                  const ushort* __restrict__ kb,
                                                  const ushort* __restrict__ vb,
                                                  const float* __restrict__ Lneg,
                                                  float* __restrict__ out) {
  const int blk = blockIdx.x;
  const int b = blk & 7, ntb = blk >> 3;
  const int nbase = ntb * 128;
  const int lane = threadIdx.x & 63, w = threadIdx.x >> 6;   // 8 waves
  const int quad = lane >> 4, l15 = lane & 15;
  const int cbase = w * 64;
  const int swz = l15 & 7;
  const int Mw = w >> 1;               // produce m-tile (0..3)
  const int Tb = (w & 1) * 4;          // produce n-tile base (0 or 4)

  __shared__ __align__(16) ushort PT[2][128 * 64];  // 32 KB; 16B-granule XOR swizzle

  const ushort* qb_b = qb + (size_t)b * 4096 * 32;
  const ushort* kb_b = kb + (size_t)b * 4096 * 32;
  const ushort* vb_b = vb + (size_t)b * 512 * 4096;
  const float* L_b = Lneg + (size_t)b * 4096;

  s16x8 kf[4];  // K rows for this wave's 4 produce n-tiles
#pragma unroll
  for (int i = 0; i < 4; ++i)
    kf[i] = *(const s16x8*)(kb_b + (size_t)(nbase + (Tb + i) * 16 + l15) * 32 + quad * 8);

  f32x4 acc[4][8];
#pragma unroll
  for (int ci = 0; ci < 4; ++ci)
#pragma unroll
    for (int nt = 0; nt < 8; ++nt) acc[ci][nt] = {0.f, 0.f, 0.f, 0.f};

  s16x8 aqp;        // prefetched q A-frag for next produce (single m-tile)
  float4 l4p;       // prefetched Lneg
  s16x8 va0[4], va1[4];  // v A-frags: m0..31 / m32..63 of current chunk

  auto loadQ = [&](int chunk) {
    const int m0 = chunk * 64;
    aqp = *(const s16x8*)(qb_b + (size_t)(m0 + Mw * 16 + l15) * 32 + quad * 8);
    l4p = *(const float4*)(L_b + m0 + Mw * 16 + quad * 4);
  };
  auto loadV0 = [&](int chunk) {
    const int m0 = chunk * 64;
#pragma unroll
    for (int ci = 0; ci < 4; ++ci)
      va0[ci] = *(const s16x8*)(vb_b + (size_t)(cbase + ci * 16 + l15) * 4096 + m0 + quad * 8);
  };
  auto loadV1 = [&](int chunk) {
    const int m0 = chunk * 64;
#pragma unroll
    for (int ci = 0; ci < 4; ++ci)
      va1[ci] = *(const s16x8*)(vb_b + (size_t)(cbase + ci * 16 + l15) * 4096 + m0 + 32 + quad * 8);
  };
  // one produce tile: QK MFMA (Lneg as C-in) -> exp2 -> pack -> ds_write.
  auto produce_tile = [&](int buf, int i) {
    char* Pw = (char*)&PT[buf][0];
    const int T = Tb + i;
    f32x4 cin; cin.x = l4p.x; cin.y = l4p.y; cin.z = l4p.z; cin.w = l4p.w;
    f32x4 s = MFMA16(aqp, kf[i], cin);               // S' + Lneg  (<= ~0)
    uint2 u;
    u.x = pack_bf16(fexp2(s.x), fexp2(s.y));
    u.y = pack_bf16(fexp2(s.z), fexp2(s.w));
    const int row = T * 16 + l15;
    const int gran = (2 * Mw + (quad >> 1)) ^ swz;
    *(uint2*)(Pw + row * 128 + gran * 16 + (quad & 1) * 8) = u;
  };

  loadQ(0);
#pragma unroll
  for (int i = 0; i < 4; ++i) produce_tile(0, i);    // prologue: produce chunk 0
  loadQ(1);
  loadV0(0);
  loadV1(0);

  for (int chunk = 0; chunk < 64; ++chunk) {
    const int buf = chunk & 1;
    chunk_barrier();   // lgkm drain + s_barrier; global prefetches stay in flight
    const char* P = (const char*)&PT[buf][0];
    // --- issue all half1 P reads (m0..31, nt 0..7) ---
    s16x8 pg[8];
#pragma unroll
    for (int nt = 0; nt < 8; ++nt)
      pg[nt] = *(const s16x8*)(P + (nt * 16 + l15) * 128 + (quad ^ swz) * 16);
    // --- produce chunk+1 into buf^1: register-only inputs, no dep on pg ---
    // (chunk 63's produce reuses aqp(63) and writes a never-read buffer: safe.)
#pragma unroll
    for (int i = 0; i < 4; ++i) produce_tile(buf ^ 1, i);
    if (chunk < 62) loadQ(chunk + 2);   // after produce (produce consumed aqp)
    // --- consume half1 (va0, m0..31) at prio 1; interleave rr issue per nt ---
    __builtin_amdgcn_s_setprio(1);
    s16x8 rr[8];
#pragma unroll
    for (int nt = 0; nt < 8; ++nt) {
#pragma unroll
      for (int ci = 0; ci < 4; ++ci) acc[ci][nt] = MFMA16(va0[ci], pg[nt], acc[ci][nt]);
      rr[nt] = *(const s16x8*)(P + (nt * 16 + l15) * 128 + ((4 + quad) ^ swz) * 16);
    }
    __builtin_amdgcn_s_setprio(0);
    // --- va0 dead: prefetch next chunk's va0 (L2 latency hides under half2) ---
    if (chunk < 63) loadV0(chunk + 1);
    // --- consume half2 (va1, m32..63) at prio 1 ---
    __builtin_amdgcn_s_setprio(1);
#pragma unroll
    for (int nt = 0; nt < 8; ++nt)
#pragma unroll
      for (int ci = 0; ci < 4; ++ci) acc[ci][nt] = MFMA16(va1[ci], rr[nt], acc[ci][nt]);
    __builtin_amdgcn_s_setprio(0);
    // --- prefetch next chunk's va1 ---
    if (chunk < 63) loadV1(chunk + 1);
  }

  float* out_b = out + (size_t)b * 512 * 4096;
#pragma unroll
  for (int ci = 0; ci < 4; ++ci)
#pragma unroll
    for (int nt = 0; nt < 8; ++nt) {
      const int n = nbase + nt * 16 + l15;
      const int c0 = cbase + ci * 16 + quad * 4;
#pragma unroll
      for (int r = 0; r < 4; ++r) out_b[(size_t)(c0 + r) * 4096 + n] = acc[ci][nt][r];
    }
}

// ---------------- launch ----------------
extern "C" void kernel_launch(void* const* d_in, const int* in_sizes, int n_in,
                              void* d_out, int out_size, void* d_ws, size_t ws_size,
                              hipStream_t stream) {
  const float* x  = (const float*)d_in[0];   // [8,512,64,64]
  const float* Wq = (const float*)d_in[1];   // [32,512]
  const float* Wk = (const float*)d_in[2];   // [32,512]
  const float* Wv = (const float*)d_in[3];   // [512,512]
  float* out = (float*)d_out;                // [8,512,64,64]

  char* ws = (char*)d_ws;
  ushort* vb  = (ushort*)(ws + 0);           // 33,554,432 B
  ushort* qb  = (ushort*)(ws + 33554432);    //  2,097,152 B
  ushort* kb  = (ushort*)(ws + 35651584);    //  2,097,152 B
  ushort* Wvb = (ushort*)(ws + 37748736);    //    524,288 B
  ushort* Wqb = (ushort*)(ws + 38273024);    //     32,768 B
  ushort* Wkb = (ushort*)(ws + 38305792);    //     32,768 B
  float*  Lrs = (float*)(ws + 38338560);     //    131,072 B  (total 38,469,632)

  hipLaunchKernelGGL(k_cvt_w, dim3(1152), dim3(256), 0, stream, Wq, Wk, Wv, Wqb, Wkb, Wvb);
  hipLaunchKernelGGL(k_proj, dim3(64, 8), dim3(256), 0, stream, x, Wqb, Wkb, Wvb, qb, kb, vb);
  hipLaunchKernelGGL(k_pass1, dim3(64, 8), dim3(256), 0, stream, qb, kb, Lrs);
  hipLaunchKernelGGL(k_pass2, dim3(256), dim3(512), 0, stream, qb, kb, vb, Lrs, out);
}

// Round 11
// 321.498 us; speedup vs baseline: 1.4579x; 1.0032x over previous
//
#include <hip/hip_runtime.h>
#include <hip/hip_bf16.h>

// SelfAttention non-local block: B=8, C=512, N=4096, CQK=32.  All-MFMA bf16 path.
// v13 = v11 pass2 (frozen) + proj store-swap + pipelined staging:
//  - accv MFMA operands swapped (A=bx, B=av): D transposes so each lane holds 4
//    consecutive n per c-row -> vb written as 32x ushort4 (8B) per thread instead
//    of 128x scalar 2B (4x fewer store instrs, same 32B segments). Fragment
//    layouts are operand-symmetric (idx=lane&15, k=quad*8) so the swap is free.
//  - staging double-buffered: U[2] ping-pong, x loads held in regs and issued one
//    sub-tile ahead -> 1 barrier/sub-tile (was 2) and HBM latency hides under the
//    previous sub-tile's phase2+pack (was 16 exposed round-trips).
//  - pass2/pass1/cvt identical to v12.
// ws: vb 33.5MB | qb 2MB | kb 2MB | Wvb 512KB | Wqb 32KB | Wkb 32KB | Lneg 128KB

typedef __attribute__((ext_vector_type(8))) short s16x8;
typedef __attribute__((ext_vector_type(4))) float f32x4;

#define MFMA16(a, b, c) __builtin_amdgcn_mfma_f32_16x16x32_bf16((a), (b), (c), 0, 0, 0)

__device__ __forceinline__ ushort f2bf(float f) {
  union { float f; unsigned u; } v; v.f = f;
  return (ushort)((v.u + 0x8000u) >> 16);
}
__device__ __forceinline__ unsigned pack_bf16(float lo, float hi) {  // (hi<<16)|lo
  union { float f; unsigned u; } a, b; a.f = lo; b.f = hi;
  return __builtin_amdgcn_perm(b.u + 0x8000u, a.u + 0x8000u, 0x07060302u);
}
__device__ __forceinline__ float fexp2(float x) { return __builtin_amdgcn_exp2f(x); }

// Raw chunk barrier: publish DS writes, sync, but leave global loads in flight.
__device__ __forceinline__ void chunk_barrier() {
  asm volatile("s_waitcnt lgkmcnt(0)" ::: "memory");
  __builtin_amdgcn_s_barrier();
  __builtin_amdgcn_sched_barrier(0);
}

// ---------------- kernel 1: weights -> bf16 (Wq pre-scaled by log2e) ----------------
__global__ void k_cvt_w(const float* __restrict__ Wq, const float* __restrict__ Wk,
                        const float* __restrict__ Wv, ushort* __restrict__ Wqb,
                        ushort* __restrict__ Wkb, ushort* __restrict__ Wvb) {
  int i = blockIdx.x * 256 + threadIdx.x;
  if (i < 262144) Wvb[i] = f2bf(Wv[i]);
  else if (i < 278528) Wqb[i - 262144] = f2bf(Wq[i - 262144] * 1.4426950408889634f);
  else if (i < 294912) Wkb[i - 278528] = f2bf(Wk[i - 278528]);
}

// ---------------- kernel 2: fused transpose + q/k/v projection ----------------
// Grid (64 ntb, 8 b), 256 thr, 2 blocks/CU. Stage x[b][512c][n0..+64] into
// XB[64 n][512 c] bf16 (XOR-swizzled 16B granules), 16 sub-tiles of 32 c,
// double-buffered U with loads issued one sub-tile ahead.
__global__ __launch_bounds__(256, 2) void k_proj(const float* __restrict__ x,
                                                 const ushort* __restrict__ Wqb,
                                                 const ushort* __restrict__ Wkb,
                                                 const ushort* __restrict__ Wvb,
                                                 ushort* __restrict__ qb,
                                                 ushort* __restrict__ kb,
                                                 ushort* __restrict__ vb) {
  const int b = blockIdx.y, n0 = blockIdx.x * 64;
  const int t = threadIdx.x;
  const int lane = t & 63, w = t >> 6;
  const int quad = lane >> 4, l15 = lane & 15;

  __shared__ __align__(16) ushort XB[64 * 512];  // [n][c] bf16, granule-swizzled; 64 KB
  __shared__ uint U[2][2][32][17];               // [buf][pair-half][c-row][c4]; 8.5 KB

  const float* x_b = x + (size_t)b * 512 * 4096;

  // staging helpers: each thread covers rows (t>>4) and 16+(t>>4), cols (t&15)*4
  auto ldX = [&](int s, float4& fa, float4& fb) {
    const int c0s = s * 32;
    const float* p = x_b + (size_t)(c0s + (t >> 4)) * 4096 + n0 + (t & 15) * 4;
    fa = *(const float4*)p;
    fb = *(const float4*)(p + (size_t)16 * 4096);
  };
  auto packU = [&](int ub, const float4& fa, const float4& fb) {
    const int cr = t >> 4, c4 = t & 15;
    U[ub][0][cr][c4] = pack_bf16(fa.x, fa.y);        // n pair (4c4, 4c4+1)
    U[ub][1][cr][c4] = pack_bf16(fa.z, fa.w);        // n pair (4c4+2, 4c4+3)
    U[ub][0][cr + 16][c4] = pack_bf16(fb.x, fb.y);
    U[ub][1][cr + 16][c4] = pack_bf16(fb.z, fb.w);
  };
  auto phase2 = [&](int ub, int s) {
    const int n = t & 63, gl = t >> 6;               // granule gl: 8 c each
    const int h = (n >> 1) & 1, c4 = n >> 2;
    const uint sel = (n & 1) ? 0x07060302u : 0x05040100u;
    uint o[4];
#pragma unroll
    for (int j = 0; j < 4; ++j) {
      uint ua = U[ub][h][gl * 8 + 2 * j][c4];
      uint ubv = U[ub][h][gl * 8 + 2 * j + 1][c4];
      o[j] = __builtin_amdgcn_perm(ubv, ua, sel);    // (bf(c_odd)<<16)|bf(c_even)
    }
    const int gfull = s * 4 + gl;                    // granule index 0..63
    const int gsw = gfull ^ (n & 7);                 // XOR swizzle (low 3 bits)
    *(uint4*)((char*)XB + n * 1024 + gsw * 16) = *(uint4*)o;
  };

  // ---- pipelined stage + transpose: 1 barrier per sub-tile ----
  float4 fa0, fb0, fa1, fb1;
  ldX(0, fa0, fb0);
  packU(0, fa0, fb0);
  ldX(1, fa1, fb1);
  __syncthreads();
#pragma unroll
  for (int s = 0; s < 16; s += 2) {
    phase2(0, s);
    if (s < 14) ldX(s + 2, fa0, fb0);
    packU(1, fa1, fb1);              // writes U[1] while phase2 read U[0]
    __syncthreads();
    phase2(1, s + 1);
    if (s < 14) {
      packU(0, fa0, fb0);            // U[0] free: all readers passed the barrier
      ldX(s + 3, fa1, fb1);
    }
    __syncthreads();
  }

  // ---- MFMA K-loop (B-frags from XB; accv operands SWAPPED) ----
  const ushort* Wqk = (w < 2) ? (Wqb + (size_t)(w * 16 + l15) * 512)
                              : (Wkb + (size_t)((w - 2) * 16 + l15) * 512);

  f32x4 accv[8][4], accqk[4];
#pragma unroll
  for (int i = 0; i < 8; ++i)
#pragma unroll
    for (int nt = 0; nt < 4; ++nt) accv[i][nt] = {0.f, 0.f, 0.f, 0.f};
#pragma unroll
  for (int nt = 0; nt < 4; ++nt) accqk[nt] = {0.f, 0.f, 0.f, 0.f};

  const char* XBb = (const char*)XB;
  for (int k0 = 0; k0 < 512; k0 += 32) {
    s16x8 bx[4];
#pragma unroll
    for (int nt = 0; nt < 4; ++nt) {
      const int nl = nt * 16 + l15;
      bx[nt] = *(const s16x8*)(XBb + nl * 1024 + ((((k0 >> 3) + quad) ^ (nl & 7)) << 4));
    }
#pragma unroll
    for (int i = 0; i < 8; ++i) {
      s16x8 av = *(const s16x8*)(Wvb + (size_t)((8 * w + i) * 16 + l15) * 512 + k0 + quad * 8);
#pragma unroll
      for (int nt = 0; nt < 4; ++nt) accv[i][nt] = MFMA16(bx[nt], av, accv[i][nt]);  // D[n][c]
    }
    s16x8 aqk = *(const s16x8*)(Wqk + k0 + quad * 8);
#pragma unroll
    for (int nt = 0; nt < 4; ++nt) accqk[nt] = MFMA16(aqk, bx[nt], accqk[nt]);
  }

  // vb store: lane holds c = (8w+i)*16+l15, n = n0+nt*16+quad*4+r  -> ushort4 along n
  ushort* vb_b = vb + (size_t)b * 512 * 4096;
#pragma unroll
  for (int i = 0; i < 8; ++i)
#pragma unroll
    for (int nt = 0; nt < 4; ++nt) {
      ushort4 u;
      u.x = f2bf(accv[i][nt][0]); u.y = f2bf(accv[i][nt][1]);
      u.z = f2bf(accv[i][nt][2]); u.w = f2bf(accv[i][nt][3]);
      *(ushort4*)(vb_b + (size_t)((8 * w + i) * 16 + l15) * 4096 + n0 + nt * 16 + quad * 4) = u;
    }

  ushort* qk_out = (w < 2) ? (qb + (size_t)b * 4096 * 32) : (kb + (size_t)b * 4096 * 32);
#pragma unroll
  for (int nt = 0; nt < 4; ++nt) {
    ushort4 u;
    u.x = f2bf(accqk[nt][0]); u.y = f2bf(accqk[nt][1]);
    u.z = f2bf(accqk[nt][2]); u.w = f2bf(accqk[nt][3]);
    *(ushort4*)(qk_out + (size_t)(n0 + nt * 16 + l15) * 32 + (w & 1) * 16 + quad * 4) = u;
  }
}

// ---------------- kernel 3: pass1 — Lneg[b][m] = -log2(sum_n 2^(S'[m,n])) ----------------
__global__ __launch_bounds__(256) void k_pass1(const ushort* __restrict__ qb,
                                               const ushort* __restrict__ kb,
                                               float* __restrict__ Lneg) {
  const int b = blockIdx.y, mt = blockIdx.x;
  const int lane = threadIdx.x & 63, w = threadIdx.x >> 6;
  const int quad = lane >> 4, l15 = lane & 15;
  const int m = mt * 64 + w * 16;
  const ushort* qb_b = qb + (size_t)b * 4096 * 32;
  const ushort* kb_b = kb + (size_t)b * 4096 * 32;
  const s16x8 aqf = *(const s16x8*)(qb_b + (size_t)(m + l15) * 32 + quad * 8);
  float ps[4] = {0.f, 0.f, 0.f, 0.f};
  const f32x4 zf = {0.f, 0.f, 0.f, 0.f};
  for (int n0 = 0; n0 < 4096; n0 += 64) {
#pragma unroll
    for (int nt = 0; nt < 4; ++nt) {
      s16x8 bk = *(const s16x8*)(kb_b + (size_t)(n0 + nt * 16 + l15) * 32 + quad * 8);
      f32x4 s = MFMA16(aqf, bk, zf);
#pragma unroll
      for (int r = 0; r < 4; ++r) ps[r] += fexp2(s[r]);
    }
  }
  for (int off = 1; off < 16; off <<= 1)
#pragma unroll
    for (int r = 0; r < 4; ++r) ps[r] += __shfl_xor(ps[r], off, 64);
  if (l15 == 0)
#pragma unroll
    for (int r = 0; r < 4; ++r)
      Lneg[(size_t)b * 4096 + m + quad * 4 + r] = -log2f(ps[r]);
}

// ---------------- kernel 4: pass2 — out = V @ 2^(S' + Lneg) ----------------
// Grid 256 = 8 b (XCD-aligned: blk&7) x 32 ntb. Block 8 waves (512 thr): tile
// 512c x 128n, chunk 64 m. Per chunk: raw barrier (lgkm only) -> issue 8 P-reads
// (m0..31) -> produce x4 (reg-only inputs) -> loadQ -> [prio1] consume half1
// (va0, rr issue per-nt) [prio0] -> loadV0 -> [prio1] consume half2 (va1)
// [prio0] -> loadV1.  Global prefetches in flight across the barrier.
__global__ __launch_bounds__(512, 2) void k_pass2(const ushort* __restrict__ qb,
                                                  const ushort* __restrict__ kb,
                                                  const ushort* __restrict__ vb,
                                                  const float* __restrict__ Lneg,
                                                  float* __restrict__ out) {
  const int blk = blockIdx.x;
  const int b = blk & 7, ntb = blk >> 3;
  const int nbase = ntb * 128;
  const int lane = threadIdx.x & 63, w = threadIdx.x >> 6;   // 8 waves
  const int quad = lane >> 4, l15 = lane & 15;
  const int cbase = w * 64;
  const int swz = l15 & 7;
  const int Mw = w >> 1;               // produce m-tile (0..3)
  const int Tb = (w & 1) * 4;          // produce n-tile base (0 or 4)

  __shared__ __align__(16) ushort PT[2][128 * 64];  // 32 KB; 16B-granule XOR swizzle

  const ushort* qb_b = qb + (size_t)b * 4096 * 32;
  const ushort* kb_b = kb + (size_t)b * 4096 * 32;
  const ushort* vb_b = vb + (size_t)b * 512 * 4096;
  const float* L_b = Lneg + (size_t)b * 4096;

  s16x8 kf[4];  // K rows for this wave's 4 produce n-tiles
#pragma unroll
  for (int i = 0; i < 4; ++i)
    kf[i] = *(const s16x8*)(kb_b + (size_t)(nbase + (Tb + i) * 16 + l15) * 32 + quad * 8);

  f32x4 acc[4][8];
#pragma unroll
  for (int ci = 0; ci < 4; ++ci)
#pragma unroll
    for (int nt = 0; nt < 8; ++nt) acc[ci][nt] = {0.f, 0.f, 0.f, 0.f};

  s16x8 aqp;        // prefetched q A-frag for next produce (single m-tile)
  float4 l4p;       // prefetched Lneg
  s16x8 va0[4], va1[4];  // v A-frags: m0..31 / m32..63 of current chunk

  auto loadQ = [&](int chunk) {
    const int m0 = chunk * 64;
    aqp = *(const s16x8*)(qb_b + (size_t)(m0 + Mw * 16 + l15) * 32 + quad * 8);
    l4p = *(const float4*)(L_b + m0 + Mw * 16 + quad * 4);
  };
  auto loadV0 = [&](int chunk) {
    const int m0 = chunk * 64;
#pragma unroll
    for (int ci = 0; ci < 4; ++ci)
      va0[ci] = *(const s16x8*)(vb_b + (size_t)(cbase + ci * 16 + l15) * 4096 + m0 + quad * 8);
  };
  auto loadV1 = [&](int chunk) {
    const int m0 = chunk * 64;
#pragma unroll
    for (int ci = 0; ci < 4; ++ci)
      va1[ci] = *(const s16x8*)(vb_b + (size_t)(cbase + ci * 16 + l15) * 4096 + m0 + 32 + quad * 8);
  };
  // one produce tile: QK MFMA (Lneg as C-in) -> exp2 -> pack -> ds_write.
  auto produce_tile = [&](int buf, int i) {
    char* Pw = (char*)&PT[buf][0];
    const int T = Tb + i;
    f32x4 cin; cin.x = l4p.x; cin.y = l4p.y; cin.z = l4p.z; cin.w = l4p.w;
    f32x4 s = MFMA16(aqp, kf[i], cin);               // S' + Lneg  (<= ~0)
    uint2 u;
    u.x = pack_bf16(fexp2(s.x), fexp2(s.y));
    u.y = pack_bf16(fexp2(s.z), fexp2(s.w));
    const int row = T * 16 + l15;
    const int gran = (2 * Mw + (quad >> 1)) ^ swz;
    *(uint2*)(Pw + row * 128 + gran * 16 + (quad & 1) * 8) = u;
  };

  loadQ(0);
#pragma unroll
  for (int i = 0; i < 4; ++i) produce_tile(0, i);    // prologue: produce chunk 0
  loadQ(1);
  loadV0(0);
  loadV1(0);

  for (int chunk = 0; chunk < 64; ++chunk) {
    const int buf = chunk & 1;
    chunk_barrier();   // lgkm drain + s_barrier; global prefetches stay in flight
    const char* P = (const char*)&PT[buf][0];
    // --- issue all half1 P reads (m0..31, nt 0..7) ---
    s16x8 pg[8];
#pragma unroll
    for (int nt = 0; nt < 8; ++nt)
      pg[nt] = *(const s16x8*)(P + (nt * 16 + l15) * 128 + (quad ^ swz) * 16);
    // --- produce chunk+1 into buf^1: register-only inputs, no dep on pg ---
    // (chunk 63's produce reuses aqp(63) and writes a never-read buffer: safe.)
#pragma unroll
    for (int i = 0; i < 4; ++i) produce_tile(buf ^ 1, i);
    if (chunk < 62) loadQ(chunk + 2);   // after produce (produce consumed aqp)
    // --- consume half1 (va0, m0..31) at prio 1; interleave rr issue per nt ---
    __builtin_amdgcn_s_setprio(1);
    s16x8 rr[8];
#pragma unroll
    for (int nt = 0; nt < 8; ++nt) {
#pragma unroll
      for (int ci = 0; ci < 4; ++ci) acc[ci][nt] = MFMA16(va0[ci], pg[nt], acc[ci][nt]);
      rr[nt] = *(const s16x8*)(P + (nt * 16 + l15) * 128 + ((4 + quad) ^ swz) * 16);
    }
    __builtin_amdgcn_s_setprio(0);
    // --- va0 dead: prefetch next chunk's va0 (L2 latency hides under half2) ---
    if (chunk < 63) loadV0(chunk + 1);
    // --- consume half2 (va1, m32..63) at prio 1 ---
    __builtin_amdgcn_s_setprio(1);
#pragma unroll
    for (int nt = 0; nt < 8; ++nt)
#pragma unroll
      for (int ci = 0; ci < 4; ++ci) acc[ci][nt] = MFMA16(va1[ci], rr[nt], acc[ci][nt]);
    __builtin_amdgcn_s_setprio(0);
    // --- prefetch next chunk's va1 ---
    if (chunk < 63) loadV1(chunk + 1);
  }

  float* out_b = out + (size_t)b * 512 * 4096;
#pragma unroll
  for (int ci = 0; ci < 4; ++ci)
#pragma unroll
    for (int nt = 0; nt < 8; ++nt) {
      const int n = nbase + nt * 16 + l15;
      const int c0 = cbase + ci * 16 + quad * 4;
#pragma unroll
      for (int r = 0; r < 4; ++r) out_b[(size_t)(c0 + r) * 4096 + n] = acc[ci][nt][r];
    }
}

// ---------------- launch ----------------
extern "C" void kernel_launch(void* const* d_in, const int* in_sizes, int n_in,
                              void* d_out, int out_size, void* d_ws, size_t ws_size,
                              hipStream_t stream) {
  const float* x  = (const float*)d_in[0];   // [8,512,64,64]
  const float* Wq = (const float*)d_in[1];   // [32,512]
  const float* Wk = (const float*)d_in[2];   // [32,512]
  const float* Wv = (const float*)d_in[3];   // [512,512]
  float* out = (float*)d_out;                // [8,512,64,64]

  char* ws = (char*)d_ws;
  ushort* vb  = (ushort*)(ws + 0);           // 33,554,432 B
  ushort* qb  = (ushort*)(ws + 33554432);    //  2,097,152 B
  ushort* kb  = (ushort*)(ws + 35651584);    //  2,097,152 B
  ushort* Wvb = (ushort*)(ws + 37748736);    //    524,288 B
  ushort* Wqb = (ushort*)(ws + 38273024);    //     32,768 B
  ushort* Wkb = (ushort*)(ws + 38305792);    //     32,768 B
  float*  Lrs = (float*)(ws + 38338560);     //    131,072 B  (total 38,469,632)

  hipLaunchKernelGGL(k_cvt_w, dim3(1152), dim3(256), 0, stream, Wq, Wk, Wv, Wqb, Wkb, Wvb);
  hipLaunchKernelGGL(k_proj, dim3(64, 8), dim3(256), 0, stream, x, Wqb, Wkb, Wvb, qb, kb, vb);
  hipLaunchKernelGGL(k_pass1, dim3(64, 8), dim3(256), 0, stream, qb, kb, Lrs);
  hipLaunchKernelGGL(k_pass2, dim3(256), dim3(512), 0, stream, qb, kb, vb, Lrs, out);
}